// Round 1
// baseline (1551.120 us; speedup 1.0000x reference)
//
#include <hip/hip_runtime.h>
#include <math.h>

#define LN_EPS 1e-5f

// ---------------------------------------------------------------------------
// Stage 1: spatial-sum reduction.
// Grid layout (3584 blocks):
//   [0,    2048): x2, 128 planes (2*64) x 16 segs of 131072 elems
//   [2048, 3072): x1, 256 planes (2*128) x 4 segs of 65536 elems
//   [3072, 3584): x0, 512 planes (2*256) x 1 seg  of 32768 elems
// Each block writes exactly one float partial to ws[blockIdx.x] -> no
// zero-init / atomics needed (ws is re-poisoned before every launch).
// ---------------------------------------------------------------------------
__global__ __launch_bounds__(256) void FusionMagic_reduce(
    const float* __restrict__ x0, const float* __restrict__ x1,
    const float* __restrict__ x2, float* __restrict__ partials)
{
    const int bid = blockIdx.x;
    const float* src;
    int segElems;
    if (bid < 2048) {                 // x2
        src = x2 + (size_t)bid * 131072u;
        segElems = 131072;
    } else if (bid < 3072) {          // x1
        src = x1 + (size_t)(bid - 2048) * 65536u;
        segElems = 65536;
    } else {                          // x0
        src = x0 + (size_t)(bid - 3072) * 32768u;
        segElems = 32768;
    }
    const int tid = threadIdx.x;
    const float4* v = (const float4*)src;
    const int n4 = segElems >> 2;
    float4 acc = make_float4(0.f, 0.f, 0.f, 0.f);
    for (int i = tid; i < n4; i += 256) {
        float4 t = v[i];
        acc.x += t.x; acc.y += t.y; acc.z += t.z; acc.w += t.w;
    }
    float s = (acc.x + acc.y) + (acc.z + acc.w);
    #pragma unroll
    for (int off = 32; off > 0; off >>= 1) s += __shfl_down(s, off, 64);
    __shared__ float wsum[4];
    if ((tid & 63) == 0) wsum[tid >> 6] = s;
    __syncthreads();
    if (tid == 0)
        partials[bid] = (wsum[0] + wsum[1]) + (wsum[2] + wsum[3]);
}

// ---------------------------------------------------------------------------
// Stage 2: tiny head. One block per batch, 448 threads (7 full waves).
// ---------------------------------------------------------------------------
__device__ __forceinline__ float block_sum448(float v, float* scratch, int t)
{
    #pragma unroll
    for (int off = 32; off > 0; off >>= 1) v += __shfl_down(v, off, 64);
    __syncthreads();                        // protect scratch from prior reads
    if ((t & 63) == 0) scratch[t >> 6] = v;
    __syncthreads();
    float s = scratch[0];
    #pragma unroll
    for (int i = 1; i < 7; i++) s += scratch[i];   // broadcast reads
    return s;
}

__device__ __forceinline__ void layernorm448(
    float* __restrict__ arr, int n,
    const float* __restrict__ w, const float* __restrict__ bia,
    float* scratch, int t)
{
    float x = (t < n) ? arr[t] : 0.f;
    float mu = block_sum448(x, scratch, t) / (float)n;
    float d = (t < n) ? (x - mu) : 0.f;
    float var = block_sum448(d * d, scratch, t) / (float)n;
    float r = rsqrtf(var + LN_EPS);
    if (t < n) arr[t] = d * r * w[t] + bia[t];
    __syncthreads();
}

__global__ __launch_bounds__(448) void FusionMagic_head(
    const float* __restrict__ partials,
    const float* __restrict__ ln1_w, const float* __restrict__ ln1_b,
    const float* __restrict__ ln2_w, const float* __restrict__ ln2_b,
    const float* __restrict__ ln3_w, const float* __restrict__ ln3_b,
    const float* __restrict__ ln4_w, const float* __restrict__ ln4_b,
    const float* __restrict__ ln5_w, const float* __restrict__ ln5_b,
    const float* __restrict__ w1, const float* __restrict__ b1,
    const float* __restrict__ w2, const float* __restrict__ b2,
    const float* __restrict__ cw, const float* __restrict__ cb,
    float* __restrict__ out)
{
    const int b = blockIdx.x;
    const int t = threadIdx.x;
    const float* px2 = partials;          // [128 planes][16]
    const float* px1 = partials + 2048;   // [256 planes][4]
    const float* px0 = partials + 3072;   // [512 planes][1]

    __shared__ float v1[64];      // ln1(gap(x2))
    __shared__ float cat[448];    // [v2(128), v3(256)] -> ln4 input (384 used)
    __shared__ float cat5[448];   // [v1(64), ln4out(384)] -> ln5
    __shared__ float h1[64];
    __shared__ float h2s[448];
    __shared__ float scratch[8];

    // raw spatial means
    if (t < 64) {
        const float* p = px2 + (size_t)(b * 64 + t) * 16u;
        float s = 0.f;
        #pragma unroll
        for (int i = 0; i < 16; i++) s += p[i];
        v1[t] = s * (1.0f / 2097152.0f);
    }
    if (t < 128) {
        const float* p = px1 + (size_t)(b * 128 + t) * 4u;
        cat[t] = ((p[0] + p[1]) + (p[2] + p[3])) * (1.0f / 262144.0f);
    }
    if (t < 256) {
        cat[128 + t] = px0[b * 256 + t] * (1.0f / 32768.0f);
    }
    __syncthreads();

    layernorm448(v1, 64, ln1_w, ln1_b, scratch, t);         // v1 = ln1
    layernorm448(cat, 128, ln2_w, ln2_b, scratch, t);       // v2 = ln2
    layernorm448(cat + 128, 256, ln3_w, ln3_b, scratch, t); // v3 = ln3
    layernorm448(cat, 384, ln4_w, ln4_b, scratch, t);       // ln4([v2,v3])

    if (t < 64) cat5[t] = v1[t];
    if (t < 384) cat5[64 + t] = cat[t];
    __syncthreads();
    layernorm448(cat5, 448, ln5_w, ln5_b, scratch, t);      // ln5([v1,ln4])

    // h1 = relu(cat5 @ w1.T + b1)  : w1 is [64,448]
    if (t < 64) {
        float s = b1[t];
        const float* wr = w1 + (size_t)t * 448u;
        for (int k = 0; k < 448; k++) s = fmaf(cat5[k], wr[k], s);
        h1[t] = fmaxf(s, 0.f);
    }
    __syncthreads();

    // h2 = relu(h1 @ w2.T + b2)   : w2 is [448,64]
    {
        float s = b2[t];
        const float* wr = w2 + (size_t)t * 64u;
        #pragma unroll 8
        for (int k = 0; k < 64; k++) s = fmaf(h1[k], wr[k], s);
        h2s[t] = fmaxf(s, 0.f);
    }
    __syncthreads();

    // o = sigmoid(h2 @ cw.T + cb) : cw is [64,448]
    if (t < 64) {
        float s = cb[t];
        const float* wr = cw + (size_t)t * 448u;
        for (int k = 0; k < 448; k++) s = fmaf(h2s[k], wr[k], s);
        out[b * 64 + t] = 1.0f / (1.0f + expf(-s));
    }
}

extern "C" void kernel_launch(void* const* d_in, const int* in_sizes, int n_in,
                              void* d_out, int out_size, void* d_ws, size_t ws_size,
                              hipStream_t stream)
{
    const float* x0 = (const float*)d_in[0];
    const float* x1 = (const float*)d_in[1];
    const float* x2 = (const float*)d_in[2];
    const float* ln1_w = (const float*)d_in[3];
    const float* ln1_b = (const float*)d_in[4];
    const float* ln2_w = (const float*)d_in[5];
    const float* ln2_b = (const float*)d_in[6];
    const float* ln3_w = (const float*)d_in[7];
    const float* ln3_b = (const float*)d_in[8];
    const float* ln4_w = (const float*)d_in[9];
    const float* ln4_b = (const float*)d_in[10];
    const float* ln5_w = (const float*)d_in[11];
    const float* ln5_b = (const float*)d_in[12];
    const float* w1 = (const float*)d_in[13];
    const float* b1 = (const float*)d_in[14];
    const float* w2 = (const float*)d_in[15];
    const float* b2 = (const float*)d_in[16];
    const float* cw = (const float*)d_in[17];
    const float* cb = (const float*)d_in[18];
    float* partials = (float*)d_ws;   // 3584 floats
    float* out = (float*)d_out;

    FusionMagic_reduce<<<3584, 256, 0, stream>>>(x0, x1, x2, partials);
    FusionMagic_head<<<2, 448, 0, stream>>>(
        partials,
        ln1_w, ln1_b, ln2_w, ln2_b, ln3_w, ln3_b, ln4_w, ln4_b, ln5_w, ln5_b,
        w1, b1, w2, b2, cw, cb, out);
}